// Round 9
// baseline (545.644 us; speedup 1.0000x reference)
//
#include <hip/hip_runtime.h>

// Swin window attention, fused one-window-per-block (R9).
// Shapes: B=64, RES=56, DIMS=192, HEADS=6, HD=32, WS=7, N=49, nW=64, SHIFT=3.
// Grid = 4096 blocks (1 window each). Block = 768 threads (12 waves, 3/SIMD).
//
// R9 vs R8 (structure frozen: 4x weight reuse, swapped vector epilogues):
//  1. Per-head P strips + explicit two-head interleave in phase 3. The unrolled
//     head loop COULD overlap, but both heads shared one P strip -> WAR hazard
//     through LDS forced write->lgkmcnt->read serialization (~120+cy x2/wave on
//     the critical path). Now: QK0,QK1,sm0,writeP0,sm1,writeP1,PV0,PV1 with
//     myp0/myp1 disjoint. LDS 159744 B (<=160K, still 1 block/CU by design).
//  2. Cross-barrier prefetch: __syncthreads is a fence, compiler can't hoist
//     global loads over it. Manually load ph2 weight frags before B0 and both
//     heads' bias rows before B1 (ph4 weights before B2 since R8). VGPR ~210
//     peak; 3 waves/SIMD budget ~680/wave -> no spill.
//
// R8: packed v_cvt_pk_bf16_f32 epilogues; setprio around MFMA clusters.
// R7: 4x weight reuse (weight frags loaded once per block) -> L2 weight traffic
// 1152->288 KB/window; bias rows padded to 52 f32 -> coalesced f32x4 gathers.
//
// Layout facts used (verified per guide):
//   A-frag: lane holds A[m=lane&15][k=(lane>>4)*8 + j], j=0..7 (16B contig)
//   B-frag: lane holds B[k=(lane>>4)*8 + j][n=lane&15]
//   C/D   : lane holds D[m=(lane>>4)*4 + r][n=lane&15], r=0..3
//   X-frag from [tok][d] LDS serves as BOTH A and B role (same lane->addr map).
// Pad rows: Q/K tokens >= 49 and V keys >= 49 zeroed at store (X LDS rows
// 49..63 are garbage; the -inf mask add in ph3 must never meet NaN/Inf).
// Mask quirk: reference repeats mask by batch (scores[b*64+w] gets mask[b]).

typedef __attribute__((ext_vector_type(8))) short bf16x8;
typedef __attribute__((ext_vector_type(4))) short short4v;
typedef __attribute__((ext_vector_type(4))) float f32x4;

__device__ __forceinline__ short f2bf(float x) {
  unsigned u = __builtin_bit_cast(unsigned, x);
  u += 0x7fffu + ((u >> 16) & 1u);   // RNE
  return (short)(u >> 16);
}

// packed f32x2 -> bf16x2 (RNE), 1 VALU op. No builtin on gfx950 (T12).
__device__ __forceinline__ unsigned cvtpk(float a, float b) {
  unsigned r;
  asm("v_cvt_pk_bf16_f32 %0, %1, %2" : "=v"(r) : "v"(a), "v"(b));
  return r;
}

// ---------------- prep: weight transpose->bf16, bias expansion ----------------
// biasx layout: [h][49][52] f32, rows padded to 52 (16B-aligned); k=49..51 zeroed.
__global__ void prep_kernel(const float* __restrict__ wq, const float* __restrict__ wk,
                            const float* __restrict__ wv, const float* __restrict__ wo,
                            const float* __restrict__ table,
                            short* __restrict__ wT, float* __restrict__ biasx) {
  int tid = blockIdx.x * 256 + threadIdx.x;
  if (tid < 4 * 36864) {
    int mat = tid / 36864, rem = tid % 36864;
    int k = rem / 192, n = rem % 192;
    const float* w = (mat == 0) ? wq : (mat == 1) ? wk : (mat == 2) ? wv : wo;
    wT[mat * 36864 + n * 192 + k] = f2bf(w[k * 192 + n]);
  }
  if (tid < 6 * 2548) {
    int h = tid / 2548, rem = tid % 2548;
    int q = rem / 52, k = rem % 52;
    float v = 0.f;
    if (k < 49) {
      int idx = ((q / 7) - (k / 7) + 6) * 13 + ((q % 7) - (k % 7) + 6);
      v = table[idx * 6 + h];
    }
    biasx[h * 2548 + q * 52 + k] = v;
  }
}

// ---------------- main fused kernel ----------------
__launch_bounds__(768, 3)
__global__ void swin_attn_kernel(const float* __restrict__ x,
                                 const short* __restrict__ wT,
                                 const float* __restrict__ biasx,
                                 const float* __restrict__ bq, const float* __restrict__ bk,
                                 const float* __restrict__ bv, const float* __restrict__ bo,
                                 float* __restrict__ out) {
  extern __shared__ short smem[];
  short* s_xo = smem;           // 64 x 200 (X, then O after phase 3)
  short* s_q  = smem + 12800;   // 64 x 200
  short* s_k  = smem + 25600;   // 64 x 200
  short* s_vt = smem + 38400;   // 192 x 72 (V transposed: [d][key])
  short* s_p  = smem + 52224;   // 12 waves x 2 heads x 16 x 72 P strips
  // total = 79872 shorts = 159744 B (<= 160 KiB, 1 block/CU)

  const int tid  = threadIdx.x;
  const int w    = tid >> 6;       // wave id 0..11
  const int lane = tid & 63;
  const int quad = lane >> 4;
  const int l15  = lane & 15;

  const int bw  = blockIdx.x;
  const int b   = bw >> 6;          // batch
  const int wi  = bw & 63;          // window in image
  const int wwh = wi >> 3, www = wi & 7;   // spatial window coords
  const int mwh = b >> 3,  mww = b & 7;    // mask window coords (reference quirk!)

  const int rt = w & 3;   // ph2: dout-tile group; ph3: query-tile
  const int g  = w >> 2;  // ph2: matrix (0=Q,1=K,2=V); ph3: head-pair

  const f32x4 zero4 = {0.f, 0.f, 0.f, 0.f};
  const float NEGINF = -__builtin_inff();
  const float SCALE = 0.17677669529663687f;  // 1/sqrt(32)

  // ---- phase 1: load shifted window x -> LDS bf16 ----
  {
    const int hb = wwh * 7 + 3, wb = www * 7 + 3;
    for (int i = tid; i < 2352; i += 768) {
      int t = i / 48, c4 = i - t * 48;
      int th = t / 7, tw = t - th * 7;
      int gh = hb + th; if (gh >= 56) gh -= 56;
      int gw = wb + tw; if (gw >= 56) gw -= 56;
      float4 v = *(const float4*)(x + (((b * 56 + gh) * 56 + gw) * 192 + c4 * 4));
      uint2 s;
      s.x = cvtpk(v.x, v.y); s.y = cvtpk(v.z, v.w);
      *(uint2*)(s_xo + t * 200 + c4 * 4) = s;
    }
  }

  // ---- prefetch ph2 weight frags BEFORE B0 (global, no LDS dependency) ----
  bf16x8 wfp[3][6];
  {
    const short* wtm = wT + g * 36864;
#pragma unroll
    for (int i = 0; i < 3; ++i) {
      const short* wrow = wtm + ((rt * 3 + i) * 16 + l15) * 192;
#pragma unroll
      for (int ks = 0; ks < 6; ++ks)
        wfp[i][ks] = *(const bf16x8*)(wrow + ks * 32 + quad * 8);
    }
  }
  __syncthreads();   // B0: X ready

  // ---- phase 2: QKV projections, 4x weight reuse ----
  // wave w: matrix g, dout-tiles rt*3..rt*3+2, ALL 4 token-tiles per dout-tile.
  {
    bf16x8 xf[4][6];
#pragma unroll
    for (int nt = 0; nt < 4; ++nt)
#pragma unroll
      for (int ks = 0; ks < 6; ++ks)
        xf[nt][ks] = *(const bf16x8*)(s_xo + (nt * 16 + l15) * 200 + ks * 32 + quad * 8);

    if (g < 2) {
      // Q/K swapped: D[dout][token] = mfma(A=W^T rows, B=X^T). Vector stores to
      // [tok][d] (4 consecutive d per lane). Pad tokens store 0.
      const float* bp = g ? bk : bq;
      short* dst = g ? s_k : s_q;
#pragma unroll
      for (int i = 0; i < 3; ++i) {
        const int dbase = (rt * 3 + i) * 16;
        f32x4 acc[4] = {zero4, zero4, zero4, zero4};
        __builtin_amdgcn_s_setprio(1);
#pragma unroll
        for (int ks = 0; ks < 6; ++ks)
#pragma unroll
          for (int nt = 0; nt < 4; ++nt)
            acc[nt] = __builtin_amdgcn_mfma_f32_16x16x32_bf16(wfp[i][ks], xf[nt][ks], acc[nt], 0, 0, 0);
        __builtin_amdgcn_s_setprio(0);
        const float4 b4 = *(const float4*)(bp + dbase + quad * 4);
#pragma unroll
        for (int nt = 0; nt < 4; ++nt) {
          const int tok = nt * 16 + l15;
          const bool tv = (tok < 49);
          float e0 = tv ? acc[nt][0] + b4.x : 0.f;
          float e1 = tv ? acc[nt][1] + b4.y : 0.f;
          float e2 = tv ? acc[nt][2] + b4.z : 0.f;
          float e3 = tv ? acc[nt][3] + b4.w : 0.f;
          uint2 st;
          st.x = cvtpk(e0, e1); st.y = cvtpk(e2, e3);
          *(uint2*)(dst + tok * 200 + dbase + quad * 4) = st;
        }
      }
    } else {
      // V unswapped: D[key][dout] = mfma(A=X, B=W). Vector stores to VT[d][key]
      // (4 consecutive keys per lane). Pad keys store 0.
#pragma unroll
      for (int i = 0; i < 3; ++i) {
        const int dbase = (rt * 3 + i) * 16;
        f32x4 acc[4] = {zero4, zero4, zero4, zero4};
        __builtin_amdgcn_s_setprio(1);
#pragma unroll
        for (int ks = 0; ks < 6; ++ks)
#pragma unroll
          for (int nt = 0; nt < 4; ++nt)
            acc[nt] = __builtin_amdgcn_mfma_f32_16x16x32_bf16(xf[nt][ks], wfp[i][ks], acc[nt], 0, 0, 0);
        __builtin_amdgcn_s_setprio(0);
        const float bvv = bv[dbase + l15];
#pragma unroll
        for (int nt = 0; nt < 4; ++nt) {
          float e[4];
#pragma unroll
          for (int r = 0; r < 4; ++r) {
            int key = nt * 16 + quad * 4 + r;
            e[r] = (key < 49) ? (acc[nt][r] + bvv) : 0.f;
          }
          uint2 st;
          st.x = cvtpk(e[0], e[1]); st.y = cvtpk(e[2], e[3]);
          *(uint2*)(s_vt + (dbase + l15) * 72 + nt * 16 + quad * 4) = st;
        }
      }
    }
  }

  // ---- ph3 constants + bias prefetch BEFORE B1 (global/VALU only) ----
  const int token = rt * 16 + l15;
  const int qc  = (token < 49) ? token : 48;
  float bmadd[4][4];
  {
    const int qth = qc / 7, qtw = qc - qth * 7;
    const int cq  = ((mwh == 7) ? (1 + (qth >= 4)) : 0) * 3
                  + ((mww == 7) ? (1 + (qtw >= 4)) : 0);
#pragma unroll
    for (int mt = 0; mt < 4; ++mt) {
#pragma unroll
      for (int r = 0; r < 4; ++r) {
        int key = mt * 16 + quad * 4 + r;
        if (key > 48) {
          bmadd[mt][r] = NEGINF;
        } else {
          int kth = key / 7, ktw = key - kth * 7;
          int ck = ((mwh == 7) ? (1 + (kth >= 4)) : 0) * 3
                 + ((mww == 7) ? (1 + (ktw >= 4)) : 0);
          bmadd[mt][r] = (ck == cq) ? 0.f : -1000.f;
        }
      }
    }
  }
  f32x4 b4h[2][4];
#pragma unroll
  for (int hh = 0; hh < 2; ++hh) {
    const float* bxr = biasx + (g * 2 + hh) * 2548 + qc * 52;
#pragma unroll
    for (int mt = 0; mt < 4; ++mt) {
      const int kc = (mt < 3) ? (mt * 16 + quad * 4) : 48;  // mt=3: clamp, -inf masks
      b4h[hh][mt] = *(const f32x4*)(bxr + kc);
    }
  }
  __syncthreads();   // B1: QKV ready; X dead

  // ---- phase 3: attention, explicit two-head interleave ----
  // wave = query-tile rt x head-pair g; heads h0=2g (d00), h1=2g+1 (d01).
  {
    short* myp0 = s_p + w * 2304;        // head-0 P strip (16x72)
    short* myp1 = myp0 + 1152;           // head-1 P strip
    const int d00 = g * 64, d01 = g * 64 + 32;
    const int qrow = (rt * 16 + l15) * 200;

    // QK^T both heads (swapped: S^T[key][query] = mfma(A=K rows, B=Q^T))
    float sv0[4][4], sv1[4][4];
    {
      bf16x8 qf0 = *(const bf16x8*)(s_q + qrow + d00 + quad * 8);
      bf16x8 qf1 = *(const bf16x8*)(s_q + qrow + d01 + quad * 8);
#pragma unroll
      for (int mt = 0; mt < 4; ++mt) {
        bf16x8 kf0 = *(const bf16x8*)(s_k + (mt * 16 + l15) * 200 + d00 + quad * 8);
        bf16x8 kf1 = *(const bf16x8*)(s_k + (mt * 16 + l15) * 200 + d01 + quad * 8);
        f32x4 s0 = __builtin_amdgcn_mfma_f32_16x16x32_bf16(kf0, qf0, zero4, 0, 0, 0);
        f32x4 s1 = __builtin_amdgcn_mfma_f32_16x16x32_bf16(kf1, qf1, zero4, 0, 0, 0);
#pragma unroll
        for (int r = 0; r < 4; ++r) {
          sv0[mt][r] = s0[r] * SCALE + b4h[0][mt][r] + bmadd[mt][r];
          sv1[mt][r] = s1[r] * SCALE + b4h[1][mt][r] + bmadd[mt][r];
        }
      }
    }
    // softmax h0 (query l15: 16 lane-local values + 2 quad shfl) -> write P0
    float inv0;
    {
      float mx = sv0[0][0];
#pragma unroll
      for (int mt = 0; mt < 4; ++mt)
#pragma unroll
        for (int r = 0; r < 4; ++r) mx = fmaxf(mx, sv0[mt][r]);
      mx = fmaxf(mx, __shfl_xor(mx, 16));
      mx = fmaxf(mx, __shfl_xor(mx, 32));
      float s0 = 0.f;
#pragma unroll
      for (int mt = 0; mt < 4; ++mt)
#pragma unroll
        for (int r = 0; r < 4; ++r) {
          float e = __expf(sv0[mt][r] - mx);
          sv0[mt][r] = e;
          s0 += e;
        }
      s0 += __shfl_xor(s0, 16);
      s0 += __shfl_xor(s0, 32);
      inv0 = 1.0f / s0;
#pragma unroll
      for (int mt = 0; mt < 4; ++mt) {
        uint2 st;
        st.x = cvtpk(sv0[mt][0], sv0[mt][1]); st.y = cvtpk(sv0[mt][2], sv0[mt][3]);
        *(uint2*)(myp0 + l15 * 72 + mt * 16 + quad * 4) = st;
      }
    }
    // softmax h1 -> write P1 (fills P0's write->read latency)
    float inv1;
    {
      float mx = sv1[0][0];
#pragma unroll
      for (int mt = 0; mt < 4; ++mt)
#pragma unroll
        for (int r = 0; r < 4; ++r) mx = fmaxf(mx, sv1[mt][r]);
      mx = fmaxf(mx, __shfl_xor(mx, 16));
      mx = fmaxf(mx, __shfl_xor(mx, 32));
      float s0 = 0.f;
#pragma unroll
      for (int mt = 0; mt < 4; ++mt)
#pragma unroll
        for (int r = 0; r < 4; ++r) {
          float e = __expf(sv1[mt][r] - mx);
          sv1[mt][r] = e;
          s0 += e;
        }
      s0 += __shfl_xor(s0, 16);
      s0 += __shfl_xor(s0, 32);
      inv1 = 1.0f / s0;
#pragma unroll
      for (int mt = 0; mt < 4; ++mt) {
        uint2 st;
        st.x = cvtpk(sv1[mt][0], sv1[mt][1]); st.y = cvtpk(sv1[mt][2], sv1[mt][3]);
        *(uint2*)(myp1 + l15 * 72 + mt * 16 + quad * 4) = st;
      }
    }
    // PV h0 (swapped: O^T[d][query] = mfma(A=V^T rows, B=P^T))
#pragma unroll
    for (int mt2 = 0; mt2 < 2; ++mt2) {
      f32x4 o = zero4;
#pragma unroll
      for (int ks = 0; ks < 2; ++ks) {
        bf16x8 vfr = *(const bf16x8*)(s_vt + (d00 + mt2 * 16 + l15) * 72 + ks * 32 + quad * 8);
        bf16x8 pfr = *(const bf16x8*)(myp0 + l15 * 72 + ks * 32 + quad * 8);
        o = __builtin_amdgcn_mfma_f32_16x16x32_bf16(vfr, pfr, o, 0, 0, 0);
      }
      uint2 st;
      st.x = cvtpk(o[0] * inv0, o[1] * inv0); st.y = cvtpk(o[2] * inv0, o[3] * inv0);
      *(uint2*)(s_xo + qrow + d00 + mt2 * 16 + quad * 4) = st;
    }
    // PV h1
#pragma unroll
    for (int mt2 = 0; mt2 < 2; ++mt2) {
      f32x4 o = zero4;
#pragma unroll
      for (int ks = 0; ks < 2; ++ks) {
        bf16x8 vfr = *(const bf16x8*)(s_vt + (d01 + mt2 * 16 + l15) * 72 + ks * 32 + quad * 8);
        bf16x8 pfr = *(const bf16x8*)(myp1 + l15 * 72 + ks * 32 + quad * 8);
        o = __builtin_amdgcn_mfma_f32_16x16x32_bf16(vfr, pfr, o, 0, 0, 0);
      }
      uint2 st;
      st.x = cvtpk(o[0] * inv1, o[1] * inv1); st.y = cvtpk(o[2] * inv1, o[3] * inv1);
      *(uint2*)(s_xo + qrow + d01 + mt2 * 16 + quad * 4) = st;
    }
  }

  // ---- prefetch phase-4 weights BEFORE B2 (independent of LDS O) ----
  const int cbase = w * 16;
  const short* wrow4 = wT + 3 * 36864 + (cbase + l15) * 192;
  bf16x8 wf4[6];
#pragma unroll
  for (int ks = 0; ks < 6; ++ks)
    wf4[ks] = *(const bf16x8*)(wrow4 + ks * 32 + quad * 8);

  __syncthreads();   // B2: O ready (cross-wave)

  // ---- phase 4: out projection (swapped), 4x weight reuse ----
  // wave w: col-tile w (16 cols), ALL 4 token-tiles. Weight frags read once.
  {
    bf16x8 ao[4][6];
#pragma unroll
    for (int nt = 0; nt < 4; ++nt)
#pragma unroll
      for (int ks = 0; ks < 6; ++ks)
        ao[nt][ks] = *(const bf16x8*)(s_xo + (nt * 16 + l15) * 200 + ks * 32 + quad * 8);

    f32x4 acc[4] = {zero4, zero4, zero4, zero4};
    __builtin_amdgcn_s_setprio(1);
#pragma unroll
    for (int ks = 0; ks < 6; ++ks)
#pragma unroll
      for (int nt = 0; nt < 4; ++nt)
        acc[nt] = __builtin_amdgcn_mfma_f32_16x16x32_bf16(wf4[ks], ao[nt][ks], acc[nt], 0, 0, 0);
    __builtin_amdgcn_s_setprio(0);

    const float4 bo4 = *(const float4*)(bo + cbase + quad * 4);
#pragma unroll
    for (int nt = 0; nt < 4; ++nt) {
      const int tok = nt * 16 + l15;
      if (tok < 49) {
        int tth = tok / 7, ttw = tok - tth * 7;
        int gh = wwh * 7 + tth + 3; if (gh >= 56) gh -= 56;
        int gw = www * 7 + ttw + 3; if (gw >= 56) gw -= 56;
        float4 v;
        v.x = acc[nt][0] + bo4.x; v.y = acc[nt][1] + bo4.y;
        v.z = acc[nt][2] + bo4.z; v.w = acc[nt][3] + bo4.w;
        *(float4*)(out + ((b * 56 + gh) * 56 + gw) * 192 + cbase + quad * 4) = v;
      }
    }
  }
}

extern "C" void kernel_launch(void* const* d_in, const int* in_sizes, int n_in,
                              void* d_out, int out_size, void* d_ws, size_t ws_size,
                              hipStream_t stream) {
  const float* x     = (const float*)d_in[0];
  const float* table = (const float*)d_in[1];
  const float* wq    = (const float*)d_in[2];
  const float* bq    = (const float*)d_in[3];
  const float* wk    = (const float*)d_in[4];
  const float* bk    = (const float*)d_in[5];
  const float* wv    = (const float*)d_in[6];
  const float* bv    = (const float*)d_in[7];
  const float* wo    = (const float*)d_in[8];
  const float* bo    = (const float*)d_in[9];
  float* out = (float*)d_out;

  short* wT    = (short*)d_ws;                       // 294912 B
  float* biasx = (float*)((char*)d_ws + 294912);     // 6*2548*4 = 61152 B

  prep_kernel<<<576, 256, 0, stream>>>(wq, wk, wv, wo, table, wT, biasx);

  const int smem_bytes = 79872 * 2;  // 159744 (<= 160 KiB)
  (void)hipFuncSetAttribute(reinterpret_cast<const void*>(swin_attn_kernel),
                            hipFuncAttributeMaxDynamicSharedMemorySize, smem_bytes);
  swin_attn_kernel<<<4096, 768, smem_bytes, stream>>>(x, wT, biasx, bq, bk, bv, bo, out);
}